// Round 6
// baseline (11986.187 us; speedup 1.0000x reference)
//
#include <hip/hip_runtime.h>
#include <hip/hip_bf16.h>

// ---------------------------------------------------------------------------
// AutoregressiveBeamDecoder: B=256, T=128, D=512, H=1024, NB=64, HH=8
// Round 6: split-bf16 MFMA with pre-packed B fragments.
//  - B (weights) packed at setup into MFMA fragment order:
//      BP[(nf*nKs + ks)*512 + lane*8 + j],  n = nf*16+(lane&15),
//      k = ks*32+(lane>>4)*8+j  -> wave B-frag load = coalesced 1KB global read
//  - A (activations) LDS double-buffered, ONE __syncthreads per K-iter,
//    register prefetch issued at loop top (hidden under MFMA section)
//  - ln_g folded into packed W_o1k (gru no longer produces hg split)
// C = Ahi@Whi + Ahi@Wlo + Alo@Whi  (3x mfma_f32_16x16x32_bf16, fp32 accum)
// ---------------------------------------------------------------------------

#define TS 68          // fp32 LDS row stride (fallback path only)
constexpr int SZ = 262144;     // 256*1024
constexpr int TT = 128;        // T
constexpr int LDA_CTX = 65536; // T*D

typedef __attribute__((ext_vector_type(8))) short short8_t;
typedef __attribute__((ext_vector_type(4))) float f32x4;

// ---------------- bf16 split helpers (bit-level, RNE) ----------------------

__device__ __forceinline__ unsigned short f2bf_rne(float v) {
    unsigned u = __float_as_uint(v);
    unsigned r = u + 0x7fffu + ((u >> 16) & 1u);
    return (unsigned short)(r >> 16);
}
__device__ __forceinline__ float bfbits2f(unsigned short h) {
    return __uint_as_float(((unsigned)h) << 16);
}
__device__ __forceinline__ void split2(float v, unsigned short& h, unsigned short& l) {
    h = f2bf_rne(v);
    l = f2bf_rne(v - bfbits2f(h));
}

// ---------------- pipelined split-bf16 MFMA tile core ----------------------
// LDSROWS rows of A (64 -> 8 waves/512thr, 32 -> 4 waves/256thr).
// Wave (wr = wid>>1, wc = wid&1) computes 16 x 64 (1 A-frag x 4 B-frags).
// Caller passes nfb = tn*8 + wc*4 (global 16-col fragment base).
// sm: ushort[2 bufs][2 hl][LDSROWS*68].

template<int LDSROWS>
__device__ __forceinline__ void mfma_pipe_tile(
    const unsigned short* __restrict__ Ah, const unsigned short* __restrict__ Al,
    int lda, int b0,
    const unsigned short* __restrict__ BPh, const unsigned short* __restrict__ BPl,
    int nKs, int nIter, int nfb, unsigned short* sm, f32x4 acc[4])
{
    const int tid = threadIdx.x, lane = tid & 63, wid = tid >> 6;
    const int wr = wid >> 1;
    const int l15 = lane & 15, kg = (lane >> 4) * 8;
    const int ar = tid >> 3, ac = (tid & 7) * 8;
    const int AS = LDSROWS * 68;

    const unsigned short* gAh = Ah + (size_t)(b0 + ar) * lda + ac;
    const unsigned short* gAl = Al + (size_t)(b0 + ar) * lda + ac;
    const unsigned short* pBh[4];
    const unsigned short* pBl[4];
#pragma unroll
    for (int ni = 0; ni < 4; ++ni) {
        pBh[ni] = BPh + ((size_t)(nfb + ni) * nKs) * 512 + lane * 8;
        pBl[ni] = BPl + ((size_t)(nfb + ni) * nKs) * 512 + lane * 8;
    }

    // prologue: stage k-tile 0 into buffer 0
    {
        short8_t rh = *(const short8_t*)(gAh);
        short8_t rl = *(const short8_t*)(gAl);
        *(short8_t*)&sm[ar * 68 + ac]      = rh;
        *(short8_t*)&sm[AS + ar * 68 + ac] = rl;
    }
    __syncthreads();

    int cur = 0;
    const int arow = (wr * 16 + l15) * 68;
    for (int i = 0; i < nIter; ++i) {
        short8_t rh, rl;
        if (i + 1 < nIter) {            // prefetch next A tile (in flight under MFMA)
            rh = *(const short8_t*)(gAh + (i + 1) * 64);
            rl = *(const short8_t*)(gAl + (i + 1) * 64);
        }
        const unsigned short* Ab = &sm[cur * 2 * AS];
#pragma unroll
        for (int ks = 0; ks < 2; ++ks) {
            short8_t a_h = *(const short8_t*)&Ab[arow + ks * 32 + kg];
            short8_t a_l = *(const short8_t*)&Ab[AS + arow + ks * 32 + kg];
            const int koff = (i * 2 + ks) * 512;
#pragma unroll
            for (int ni = 0; ni < 4; ++ni) {
                short8_t b_h = *(const short8_t*)(pBh[ni] + koff);
                short8_t b_l = *(const short8_t*)(pBl[ni] + koff);
                acc[ni] = __builtin_amdgcn_mfma_f32_16x16x32_bf16(a_h, b_h, acc[ni], 0, 0, 0);
                acc[ni] = __builtin_amdgcn_mfma_f32_16x16x32_bf16(a_h, b_l, acc[ni], 0, 0, 0);
                acc[ni] = __builtin_amdgcn_mfma_f32_16x16x32_bf16(a_l, b_h, acc[ni], 0, 0, 0);
            }
        }
        if (i + 1 < nIter) {
            unsigned short* An = &sm[(cur ^ 1) * 2 * AS];
            *(short8_t*)&An[ar * 68 + ac]      = rh;
            *(short8_t*)&An[AS + ar * 68 + ac] = rl;
        }
        __syncthreads();
        cur ^= 1;
    }
}

// ---------------- fp32 tiled GEMM core (setup + fallback) ------------------

__device__ __forceinline__ void gemm_tile64(
    const float* __restrict__ A, int lda, int Mlim, int b0,
    const float* __restrict__ W, int ldw, int n0, int K,
    float* At, float* Wt, float acc[4][4])
{
    const int tid = threadIdx.x;
    const int tx = tid & 15, ty = tid >> 4;
    const int r = tid >> 2, c0 = (tid & 3) << 2;
    for (int k0 = 0; k0 < K; k0 += 16) {
        float4 av = make_float4(0.f, 0.f, 0.f, 0.f);
        if (b0 + r < Mlim)
            av = *(const float4*)(A + (size_t)(b0 + r) * lda + k0 + c0);
        float4 wv = *(const float4*)(W + (size_t)(n0 + r) * ldw + k0 + c0);
        __syncthreads();
        At[(c0+0)*TS + r] = av.x; At[(c0+1)*TS + r] = av.y;
        At[(c0+2)*TS + r] = av.z; At[(c0+3)*TS + r] = av.w;
        Wt[(c0+0)*TS + r] = wv.x; Wt[(c0+1)*TS + r] = wv.y;
        Wt[(c0+2)*TS + r] = wv.z; Wt[(c0+3)*TS + r] = wv.w;
        __syncthreads();
#pragma unroll
        for (int kk = 0; kk < 16; ++kk) {
            float4 a = *(const float4*)(At + kk*TS + ty*4);
            float4 w = *(const float4*)(Wt + kk*TS + tx*4);
            acc[0][0] += a.x*w.x; acc[0][1] += a.x*w.y; acc[0][2] += a.x*w.z; acc[0][3] += a.x*w.w;
            acc[1][0] += a.y*w.x; acc[1][1] += a.y*w.y; acc[1][2] += a.y*w.z; acc[1][3] += a.y*w.w;
            acc[2][0] += a.z*w.x; acc[2][1] += a.z*w.y; acc[2][2] += a.z*w.z; acc[2][3] += a.z*w.w;
            acc[3][0] += a.w*w.x; acc[3][1] += a.w*w.y; acc[3][2] += a.w*w.z; acc[3][3] += a.w*w.w;
        }
    }
}

// -------------------- setup kernels ----------------------------------------

__global__ void pre0_kernel(const float* __restrict__ ctx, const int* __restrict__ bh,
                            const float* __restrict__ be, float* __restrict__ A0,
                            int* __restrict__ prev)
{
    int b = blockIdx.x, tid = threadIdx.x; // blockDim 512
    float s = 0.f;
    for (int t = 0; t < TT; ++t) s += ctx[(size_t)b * LDA_CTX + t * 512 + tid];
    A0[b * 1024 + tid] = s * (1.f / 128.f);
    float s2 = 0.f;
    for (int i = 0; i < 8; ++i) s2 += be[bh[b * 8 + i] * 512 + tid];
    A0[b * 1024 + 512 + tid] = s2 * 0.125f;
    if (tid == 0) prev[b] = bh[b * 8 + 7];
}

__global__ void copy_gb_kernel(const float* g, const float* bb, float* gb)
{
    int idx = blockIdx.x * 256 + threadIdx.x; // 8 blocks
    if (idx < 1024) gb[idx] = g[idx];
    else            gb[idx] = bb[idx - 1024];
}

__global__ void wo2t_kernel(const float* __restrict__ W_o2, float* __restrict__ Wo2t)
{
    int idx = blockIdx.x * 256 + threadIdx.x; // 256 blocks -> 65536
    int k = idx >> 6, n = idx & 63;
    Wo2t[idx] = W_o2[n * 1024 + k];
}

// pack weight [N x K] (row stride ld, col offset col0, optional per-k scale)
// into MFMA fragment order + hi/lo split.
__global__ void packb_kernel(const float* __restrict__ src, int ld, int col0,
                             int N, int K, const float* __restrict__ scale,
                             unsigned short* __restrict__ ph,
                             unsigned short* __restrict__ pl)
{
    int idx = blockIdx.x * 256 + threadIdx.x;
    if (idx >= N * K) return;
    int j = idx & 7;
    int lane = (idx >> 3) & 63;
    int fs = idx >> 9;                 // nf*nKs + ks
    int nKs = K >> 5;
    int nf = fs / nKs, ks = fs - nf * nKs;
    int n = nf * 16 + (lane & 15);
    int k = ks * 32 + (lane >> 4) * 8 + j;
    float v = src[(size_t)n * ld + col0 + k];
    if (scale) v *= scale[k];
    unsigned short h, l;
    split2(v, h, l);
    ph[idx] = h; pl[idx] = l;
}

// split a matrix [N x K] into flat hi/lo (activations)
__global__ void wsplit_kernel(const float* __restrict__ src, int src_ld, int col0,
                              int N, int K, unsigned short* __restrict__ hi,
                              unsigned short* __restrict__ lo)
{
    int idx = blockIdx.x * 256 + threadIdx.x;
    if (idx >= N * K) return;
    int n = idx / K, k = idx - n * K;
    float v = src[(size_t)n * src_ld + col0 + k];
    unsigned short h, l;
    split2(v, h, l);
    hi[idx] = h; lo[idx] = l;
}

// generic small fp32 GEMM (M may be < 64); act: 0 none, 1 tanh
__global__ void gemm64_kernel(const float* __restrict__ A, int lda, int M,
                              const float* __restrict__ W, int ldw, int K,
                              const float* __restrict__ bias,
                              float* __restrict__ C, int ldc, int act)
{
    __shared__ __align__(16) float At[16 * TS];
    __shared__ __align__(16) float Wt[16 * TS];
    float acc[4][4] = {};
    int b0 = blockIdx.x * 64, n0 = blockIdx.y * 64;
    gemm_tile64(A, lda, M, b0, W, ldw, n0, K, At, Wt, acc);
    int tx = threadIdx.x & 15, ty = threadIdx.x >> 4;
#pragma unroll
    for (int i = 0; i < 4; ++i) {
        int b = b0 + ty * 4 + i;
        if (b >= M) continue;
#pragma unroll
        for (int j = 0; j < 4; ++j) {
            int n = n0 + tx * 4 + j;
            float v = acc[i][j] + (bias ? bias[n] : 0.f);
            if (act == 1) v = tanhf(v);
            C[(size_t)b * ldc + n] = v;
        }
    }
}

// x0 = relu(cin0 + bpart[prev]) -> split
__global__ void xbuild0s_kernel(const float* __restrict__ cin0, const float* __restrict__ bpart,
                                const int* __restrict__ prev,
                                unsigned short* __restrict__ xh, unsigned short* __restrict__ xl)
{
    int b = blockIdx.x, tid = threadIdx.x;
    int pb = prev[b];
#pragma unroll
    for (int jj = 0; jj < 4; ++jj) {
        int j = jj * 256 + tid;
        float v = fmaxf(cin0[(size_t)b * 1024 + j] + bpart[(size_t)pb * 1024 + j], 0.f);
        unsigned short h, l;
        split2(v, h, l);
        xh[(size_t)b * 1024 + j] = h;
        xl[(size_t)b * 1024 + j] = l;
    }
}

// fp32 xbuild (fallback)
__global__ void xbuild0_kernel(const float* __restrict__ cin0, const float* __restrict__ bpart,
                               const int* __restrict__ prev, float* __restrict__ x)
{
    int b = blockIdx.x, tid = threadIdx.x;
    int pb = prev[b];
#pragma unroll
    for (int jj = 0; jj < 4; ++jj) {
        int j = jj * 256 + tid;
        x[(size_t)b * 1024 + j] = fmaxf(cin0[(size_t)b * 1024 + j] + bpart[(size_t)pb * 1024 + j], 0.f);
    }
}

// -------------------- per-step MFMA kernels (round 6) ----------------------

// Fused 8-way GEMM; 1-D grid 256: bid = z*32 + tm*8 + tn.
// z 0..5: gate GEMMs (g=z%3, s=z/3); z=6: cin[t+1]; z=7: octx[t].
__global__ __launch_bounds__(512, 2) void gates6_kernel(
    const unsigned short* __restrict__ xh, const unsigned short* __restrict__ xl,
    const unsigned short* __restrict__ hh, const unsigned short* __restrict__ hl,
    const unsigned short* __restrict__ ctxh, const unsigned short* __restrict__ ctxl,
    const unsigned short* __restrict__ wihP_h, const unsigned short* __restrict__ wihP_l,
    const unsigned short* __restrict__ whhP_h, const unsigned short* __restrict__ whhP_l,
    const unsigned short* __restrict__ wcinP_h, const unsigned short* __restrict__ wcinP_l,
    const unsigned short* __restrict__ wo1cP_h, const unsigned short* __restrict__ wo1cP_l,
    const float* __restrict__ b_in, const float* __restrict__ b_o1,
    float* __restrict__ g6, float* __restrict__ cin, float* __restrict__ octx,
    int t)
{
    const int bid = blockIdx.x;
    const int z  = bid >> 5;
    const int tm = (bid >> 3) & 3;
    const int tn = bid & 7;
    if (z == 6 && t + 1 >= TT) return;
    const int b0 = tm * 64, n0 = tn * 128;

    const unsigned short *Ah, *Al, *BPh, *BPl;
    int lda, nKs, nIter;
    const float* bias = nullptr;
    float* C;
    if (z < 6) {
        int g = z % 3, s = z / 3;
        Ah = s ? hh : xh; Al = s ? hl : xl; lda = 1024;
        BPh = (s ? whhP_h : wihP_h) + (size_t)g * 1048576;
        BPl = (s ? whhP_l : wihP_l) + (size_t)g * 1048576;
        nKs = 32; nIter = 16;
        C = g6 + (size_t)z * SZ;
    } else if (z == 6) {
        int s = (t + 1) & 1;
        Ah = ctxh + (size_t)s * 131072; Al = ctxl + (size_t)s * 131072;
        lda = 512; nKs = 16; nIter = 8;
        BPh = wcinP_h; BPl = wcinP_l; bias = b_in; C = cin;
    } else {
        int s = t & 1;
        Ah = ctxh + (size_t)s * 131072; Al = ctxl + (size_t)s * 131072;
        lda = 512; nKs = 16; nIter = 8;
        BPh = wo1cP_h; BPl = wo1cP_l; bias = b_o1; C = octx;
    }

    __shared__ __align__(16) unsigned short sm[2 * 2 * 64 * 68];
    const int lane = threadIdx.x & 63, wid = threadIdx.x >> 6;
    const int wr = wid >> 1, wc = wid & 1;
    const int nfb = tn * 8 + wc * 4;

    f32x4 acc[4] = {};
    mfma_pipe_tile<64>(Ah, Al, lda, b0, BPh, BPl, nKs, nIter, nfb, sm, acc);

    const int l15 = lane & 15, g4 = (lane >> 4) * 4;
#pragma unroll
    for (int ni = 0; ni < 4; ++ni) {
        int col = n0 + wc * 64 + ni * 16 + l15;
        float bv = bias ? bias[col] : 0.f;
#pragma unroll
        for (int r = 0; r < 4; ++r) {
            int row = b0 + wr * 16 + g4 + r;
            C[(size_t)row * 1024 + col] = acc[ni][r] + bv;
        }
    }
}

// o-GEMM (h @ Wg^T) with folded LN epilogue; grid 64: bid = tm*8 + tn
__global__ __launch_bounds__(256, 2) void kb6_kernel(
    const unsigned short* __restrict__ hh, const unsigned short* __restrict__ hl,
    const unsigned short* __restrict__ wo1kP_h, const unsigned short* __restrict__ wo1kP_l,
    const float* __restrict__ uv, const float* __restrict__ octx,
    const float* __restrict__ mbuf, const float* __restrict__ isbuf,
    float* __restrict__ o)
{
    const int bid = blockIdx.x;
    const int tm = bid >> 3, tn = bid & 7;
    const int b0 = tm * 32, n0 = tn * 128;

    __shared__ __align__(16) unsigned short sm[2 * 2 * 32 * 68];
    const int lane = threadIdx.x & 63, wid = threadIdx.x >> 6;
    const int wr = wid >> 1, wc = wid & 1;
    const int nfb = tn * 8 + wc * 4;

    f32x4 acc[4] = {};
    mfma_pipe_tile<32>(hh, hl, 1024, b0, wo1kP_h, wo1kP_l, 32, 16, nfb, sm, acc);

    const int l15 = lane & 15, g4 = (lane >> 4) * 4;
#pragma unroll
    for (int ni = 0; ni < 4; ++ni) {
        int col = n0 + wc * 64 + ni * 16 + l15;
        float u = uv[col], vb = uv[1024 + col];
#pragma unroll
        for (int r = 0; r < 4; ++r) {
            int row = b0 + wr * 16 + g4 + r;
            float m = mbuf[row], is = isbuf[row];
            float v = (acc[ni][r] - m * u) * is + vb + octx[(size_t)row * 1024 + col];
            o[(size_t)row * 1024 + col] = fmaxf(v, 0.f);
        }
    }
}

// GRU combine + LN stats; writes h fp32 in-place + split h
__global__ void gru_ln6_kernel(const float* __restrict__ g6,
                               const float* __restrict__ b_ih, const float* __restrict__ b_hh,
                               float* __restrict__ h,
                               unsigned short* __restrict__ hh, unsigned short* __restrict__ hl,
                               float* __restrict__ mbuf, float* __restrict__ isbuf)
{
    __shared__ float ls[4], lq[4];
    int b = blockIdx.x, tid = threadIdx.x;
    float s = 0.f, q = 0.f;
#pragma unroll
    for (int jj = 0; jj < 4; ++jj) {
        int j = jj * 256 + tid;
        size_t base = (size_t)b * 1024 + j;
        float xr = g6[0 * (size_t)SZ + base] + b_ih[j];
        float xz = g6[1 * (size_t)SZ + base] + b_ih[1024 + j];
        float xn = g6[2 * (size_t)SZ + base] + b_ih[2048 + j];
        float hr = g6[3 * (size_t)SZ + base] + b_hh[j];
        float hz = g6[4 * (size_t)SZ + base] + b_hh[1024 + j];
        float hn = g6[5 * (size_t)SZ + base] + b_hh[2048 + j];
        float r = 1.f / (1.f + expf(-(xr + hr)));
        float z = 1.f / (1.f + expf(-(xz + hz)));
        float nn = tanhf(xn + r * hn);
        float ho = h[base];
        float hv = (1.f - z) * nn + z * ho;
        h[base] = hv;
        unsigned short a, c;
        split2(hv, a, c); hh[base] = a; hl[base] = c;
        s += hv; q += hv * hv;
    }
    for (int off = 32; off; off >>= 1) {
        s += __shfl_down(s, off);
        q += __shfl_down(q, off);
    }
    int lane = tid & 63, w = tid >> 6;
    if (lane == 0) { ls[w] = s; lq[w] = q; }
    __syncthreads();
    if (tid == 0) {
        float S = ls[0] + ls[1] + ls[2] + ls[3];
        float Q = lq[0] + lq[1] + lq[2] + lq[3];
        float m = S * (1.f / 1024.f);
        mbuf[b] = m;
        isbuf[b] = rsqrtf(Q * (1.f / 1024.f) - m * m + 1e-5f);
    }
}

// logits + argmax + next-x build + ctx split; 64 blocks x 256 thr, 4 rows each
__global__ void kc2_kernel(const float* __restrict__ o, const float* __restrict__ Wo2t,
                           const float* __restrict__ b_o2, const float* __restrict__ cin,
                           const float* __restrict__ bpart, const float* __restrict__ ctx,
                           unsigned short* __restrict__ xh, unsigned short* __restrict__ xl,
                           unsigned short* __restrict__ ctxh, unsigned short* __restrict__ ctxl,
                           int* __restrict__ prev, float* __restrict__ out, int t)
{
    __shared__ __align__(16) float os[4][1024];
    __shared__ float red[4][4][64];
    __shared__ int sidx[4];
    const int b0 = blockIdx.x * 4, tid = threadIdx.x;

#pragma unroll
    for (int i = 0; i < 4; ++i) {
        int f = tid + i * 256;             // float4 index, 0..1023
        int r = f >> 8, c4 = (f & 255) << 2;
        *(float4*)&os[r][c4] = *(const float4*)(o + (size_t)(b0 + r) * 1024 + c4);
    }
    __syncthreads();

    {
        int n = tid & 63, seg = tid >> 6;
        float p0 = 0.f, p1 = 0.f, p2 = 0.f, p3 = 0.f;
        int k0 = seg * 256;
        for (int k = k0; k < k0 + 256; ++k) {
            float w = Wo2t[(size_t)k * 64 + n];
            p0 += os[0][k] * w; p1 += os[1][k] * w;
            p2 += os[2][k] * w; p3 += os[3][k] * w;
        }
        red[0][seg][n] = p0; red[1][seg][n] = p1;
        red[2][seg][n] = p2; red[3][seg][n] = p3;
    }
    __syncthreads();

    {
        int r = tid >> 6, n = tid & 63;
        float lg = red[r][0][n] + red[r][1][n] + red[r][2][n] + red[r][3][n] + b_o2[n];
        out[(size_t)(b0 + r) * (TT * 64) + t * 64 + n] = lg;
        float v = lg; int idx = n;
        for (int off = 32; off; off >>= 1) {
            float ov = __shfl_xor(v, off);
            int oi = __shfl_xor(idx, off);
            if (ov > v || (ov == v && oi < idx)) { v = ov; idx = oi; }
        }
        if (n == 0) { prev[b0 + r] = idx; sidx[r] = idx; }
    }
    __syncthreads();

    if (t + 1 < TT) {
#pragma unroll
        for (int i = 0; i < 16; ++i) {
            int idx = tid + i * 256;       // 0..4095
            int r = idx >> 10, j = idx & 1023;
            float v = fmaxf(cin[(size_t)(b0 + r) * 1024 + j] +
                            bpart[(size_t)sidx[r] * 1024 + j], 0.f);
            unsigned short h, l;
            split2(v, h, l);
            xh[(size_t)(b0 + r) * 1024 + j] = h;
            xl[(size_t)(b0 + r) * 1024 + j] = l;
        }
    }
    if (t + 2 < TT) {
        int slot = t & 1;
#pragma unroll
        for (int i = 0; i < 8; ++i) {
            int idx = tid + i * 256;       // 0..2047
            int r = idx >> 9, j = idx & 511;
            float v = ctx[(size_t)(b0 + r) * LDA_CTX + (t + 2) * 512 + j];
            unsigned short h, l;
            split2(v, h, l);
            ctxh[(size_t)slot * 131072 + (size_t)(b0 + r) * 512 + j] = h;
            ctxl[(size_t)slot * 131072 + (size_t)(b0 + r) * 512 + j] = l;
        }
    }
}

// -------------------- fallback fp32 step kernels (round 1) -----------------

__global__ void step_gemms_kernel(
    const float* __restrict__ x, const float* __restrict__ hBase,
    const float* __restrict__ ctx,
    const float* __restrict__ Wih, const float* __restrict__ Whh,
    const float* __restrict__ Win, const float* __restrict__ Wo1,
    const float* __restrict__ b_in, const float* __restrict__ b_o1,
    float* __restrict__ g6, float* __restrict__ cinBase, float* __restrict__ octx,
    int t)
{
    __shared__ __align__(16) float At[16 * TS];
    __shared__ __align__(16) float Wt[16 * TS];
    float acc[4][4] = {};
    const int z = blockIdx.z, b0 = blockIdx.x * 64, n0 = blockIdx.y * 64;
    const float *A, *W, *bias = nullptr;
    float* C;
    int lda, ldw, K;
    if (z < 6) {
        int g = z % 3, s = z / 3;
        A = s ? (hBase + (size_t)(t & 1) * SZ) : x;
        lda = 1024;
        W = (s ? Whh : Wih) + (size_t)(g * 1024) * 1024;
        ldw = 1024; K = 1024;
        C = g6 + (size_t)z * SZ;
    } else if (z == 6) {
        if (t + 1 >= TT) return;
        A = ctx + (size_t)(t + 1) * 512; lda = LDA_CTX;
        W = Win; ldw = 1024; K = 512; bias = b_in;
        C = cinBase + (size_t)((t + 1) & 1) * SZ;
    } else {
        A = ctx + (size_t)t * 512; lda = LDA_CTX;
        W = Wo1 + 1024; ldw = 1536; K = 512; bias = b_o1;
        C = octx;
    }
    gemm_tile64(A, lda, 256, b0, W, ldw, n0, K, At, Wt, acc);
    int tx = threadIdx.x & 15, ty = threadIdx.x >> 4;
#pragma unroll
    for (int i = 0; i < 4; ++i) {
        int b = b0 + ty * 4 + i;
#pragma unroll
        for (int j = 0; j < 4; ++j) {
            int n = n0 + tx * 4 + j;
            float v = acc[i][j];
            if (bias) v += bias[n];
            C[(size_t)b * 1024 + n] = v;
        }
    }
}

__global__ void kb_kernel(const float* __restrict__ hg, const float* __restrict__ Wo1,
                          const float* __restrict__ uv, const float* __restrict__ octx,
                          const float* __restrict__ mbuf, const float* __restrict__ isbuf,
                          float* __restrict__ o)
{
    __shared__ __align__(16) float At[16 * TS];
    __shared__ __align__(16) float Wt[16 * TS];
    float acc[2][4] = {};
    const int b0 = blockIdx.x * 32, n0 = blockIdx.y * 64;
    const int tid = threadIdx.x, tx = tid & 15, ty = tid >> 4;
    const int r = tid >> 2, c0 = (tid & 3) << 2;
    for (int k0 = 0; k0 < 1024; k0 += 16) {
        float4 av = make_float4(0.f, 0.f, 0.f, 0.f);
        if (r < 32) av = *(const float4*)(hg + (size_t)(b0 + r) * 1024 + k0 + c0);
        float4 wv = *(const float4*)(Wo1 + (size_t)(n0 + r) * 1536 + k0 + c0);
        __syncthreads();
        At[(c0+0)*TS + r] = av.x; At[(c0+1)*TS + r] = av.y;
        At[(c0+2)*TS + r] = av.z; At[(c0+3)*TS + r] = av.w;
        Wt[(c0+0)*TS + r] = wv.x; Wt[(c0+1)*TS + r] = wv.y;
        Wt[(c0+2)*TS + r] = wv.z; Wt[(c0+3)*TS + r] = wv.w;
        __syncthreads();
#pragma unroll
        for (int kk = 0; kk < 16; ++kk) {
            float2 a = *(const float2*)(At + kk*TS + ty*2);
            float4 w = *(const float4*)(Wt + kk*TS + tx*4);
            acc[0][0] += a.x*w.x; acc[0][1] += a.x*w.y; acc[0][2] += a.x*w.z; acc[0][3] += a.x*w.w;
            acc[1][0] += a.y*w.x; acc[1][1] += a.y*w.y; acc[1][2] += a.y*w.z; acc[1][3] += a.y*w.w;
        }
    }
#pragma unroll
    for (int i = 0; i < 2; ++i) {
        int b = b0 + ty * 2 + i;
        float m = mbuf[b], is = isbuf[b];
#pragma unroll
        for (int j = 0; j < 4; ++j) {
            int n = n0 + tx * 4 + j;
            float v = (acc[i][j] - m * uv[n]) * is + uv[1024 + n] + octx[(size_t)b * 1024 + n];
            o[(size_t)b * 1024 + n] = fmaxf(v, 0.f);
        }
    }
}

__global__ void gru_ln_kernel(const float* __restrict__ g6,
                              const float* __restrict__ b_ih, const float* __restrict__ b_hh,
                              float* __restrict__ hBase, const float* __restrict__ ln_g,
                              float* __restrict__ hg, float* __restrict__ mbuf,
                              float* __restrict__ isbuf, int t)
{
    __shared__ float rs[256], rq[256];
    int b = blockIdx.x, tid = threadIdx.x;
    const float* hc = hBase + (size_t)(t & 1) * SZ + (size_t)b * 1024;
    float* hnx = hBase + (size_t)((t + 1) & 1) * SZ + (size_t)b * 1024;
    float s = 0.f, q = 0.f;
#pragma unroll
    for (int jj = 0; jj < 4; ++jj) {
        int j = jj * 256 + tid;
        size_t base = (size_t)b * 1024 + j;
        float xr = g6[0 * (size_t)SZ + base] + b_ih[j];
        float xz = g6[1 * (size_t)SZ + base] + b_ih[1024 + j];
        float xn = g6[2 * (size_t)SZ + base] + b_ih[2048 + j];
        float hr = g6[3 * (size_t)SZ + base] + b_hh[j];
        float hz = g6[4 * (size_t)SZ + base] + b_hh[1024 + j];
        float hn = g6[5 * (size_t)SZ + base] + b_hh[2048 + j];
        float r = 1.f / (1.f + expf(-(xr + hr)));
        float z = 1.f / (1.f + expf(-(xz + hz)));
        float nn = tanhf(xn + r * hn);
        float ho = hc[j];
        float hv = (1.f - z) * nn + z * ho;
        hnx[j] = hv;
        hg[base] = hv * ln_g[j];
        s += hv; q += hv * hv;
    }
    rs[tid] = s; rq[tid] = q;
    __syncthreads();
    for (int st = 128; st; st >>= 1) {
        if (tid < st) { rs[tid] += rs[tid + st]; rq[tid] += rq[tid + st]; }
        __syncthreads();
    }
    if (tid == 0) {
        float m = rs[0] * (1.f / 1024.f);
        float var = rq[0] * (1.f / 1024.f) - m * m;
        mbuf[b] = m;
        isbuf[b] = rsqrtf(var + 1e-5f);
    }
}

__global__ void kc_kernel(const float* __restrict__ o, const float* __restrict__ Wo2t,
                          const float* __restrict__ b_o2, const float* __restrict__ cinBase,
                          const float* __restrict__ bpart, float* __restrict__ x,
                          int* __restrict__ prev, float* __restrict__ out, int t)
{
    __shared__ __align__(16) float os[1024];
    __shared__ float red[4][64];
    __shared__ int sidx;
    int b = blockIdx.x, tid = threadIdx.x;
    const float* orow = o + (size_t)b * 1024;
    *(float4*)&os[tid * 4] = *(const float4*)&orow[tid * 4];
    __syncthreads();
    int n = tid & 63, seg = tid >> 6;
    float p = 0.f;
    int k0 = seg * 256;
#pragma unroll 8
    for (int k = 0; k < 256; ++k) p += os[k0 + k] * Wo2t[(size_t)(k0 + k) * 64 + n];
    red[seg][n] = p;
    __syncthreads();
    if (tid < 64) {
        float lg = red[0][tid] + red[1][tid] + red[2][tid] + red[3][tid] + b_o2[tid];
        out[((size_t)b * TT + t) * 64 + tid] = lg;
        float v = lg; int idx = tid;
        for (int off = 32; off; off >>= 1) {
            float ov = __shfl_xor(v, off);
            int oi = __shfl_xor(idx, off);
            if (ov > v || (ov == v && oi < idx)) { v = ov; idx = oi; }
        }
        if (tid == 0) { prev[b] = idx; sidx = idx; }
    }
    __syncthreads();
    if (t + 1 < TT) {
        int pb = sidx;
        const float* cn = cinBase + (size_t)((t + 1) & 1) * SZ + (size_t)b * 1024;
        const float* bp = bpart + (size_t)pb * 1024;
#pragma unroll
        for (int jj = 0; jj < 4; ++jj) {
            int j = jj * 256 + tid;
            x[(size_t)b * 1024 + j] = fmaxf(cn[j] + bp[j], 0.f);
        }
    }
}

// ---------------------------------------------------------------------------

extern "C" void kernel_launch(void* const* d_in, const int* in_sizes, int n_in,
                              void* d_out, int out_size, void* d_ws, size_t ws_size,
                              hipStream_t stream)
{
    const float* ctx    = (const float*)d_in[0];
    const int*   bh     = (const int*)d_in[1];
    const float* be     = (const float*)d_in[2];
    const float* W_in   = (const float*)d_in[3];
    const float* b_in   = (const float*)d_in[4];
    const float* W_init = (const float*)d_in[5];
    const float* b_init = (const float*)d_in[6];
    const float* W_ih   = (const float*)d_in[7];
    const float* b_ih   = (const float*)d_in[8];
    const float* W_hh   = (const float*)d_in[9];
    const float* b_hh   = (const float*)d_in[10];
    const float* ln_g   = (const float*)d_in[11];
    const float* ln_b   = (const float*)d_in[12];
    const float* W_o1   = (const float*)d_in[13];
    const float* b_o1   = (const float*)d_in[14];
    const float* W_o2   = (const float*)d_in[15];
    const float* b_o2   = (const float*)d_in[16];
    float* out = (float*)d_out;
    float* ws  = (float*)d_ws;

    const bool mfma_path = (ws_size >= 49830000ull);

    if (mfma_path) {
        float* A0    = ws;                 // setup only; aliases obuf
        float* obuf  = ws;
        float* hbuf  = ws + 262144;        // h fp32 (in-place)
        float* cin   = ws + 524288;
        float* octx  = ws + 786432;
        float* g6    = ws + 1048576;       // 6 slots
        float* bpart = ws + 2621440;       // 64x1024
        float* uvv   = ws + 2686976;       // 2x1024
        float* gb    = ws + 2689024;       // 2x1024
        float* Wo2t  = ws + 2691072;       // 1024x64
        float* mbuf  = ws + 2756608;
        float* isbuf = ws + 2756864;
        int*   prev  = (int*)(ws + 2757120);
        unsigned short* bf = (unsigned short*)(ws + 2757632);
        unsigned short* wihP_h  = bf;                  // packed, 3x[1024x1024]
        unsigned short* wihP_l  = bf + 3145728;
        unsigned short* whhP_h  = bf + 6291456;
        unsigned short* whhP_l  = bf + 9437184;
        unsigned short* wo1kP_h = bf + 12582912;       // packed, g-scaled
        unsigned short* wo1kP_l = bf + 13631488;
        unsigned short* wo1cP_h = bf + 14680064;
        unsigned short* wo1cP_l = bf + 15204352;
        unsigned short* wcinP_h = bf + 15728640;
        unsigned short* wcinP_l = bf + 16252928;
        unsigned short* xh   = bf + 16777216;
        unsigned short* xl   = bf + 17039360;
        unsigned short* hh   = bf + 17301504;
        unsigned short* hl   = bf + 17563648;
        unsigned short* ctxh = bf + 18350080;   // [2][256][512]
        unsigned short* ctxl = bf + 18612224;

        // ---- setup ----
        pre0_kernel<<<256, 512, 0, stream>>>(ctx, bh, be, A0, prev);
        copy_gb_kernel<<<8, 256, 0, stream>>>(ln_g, ln_b, gb);
        wo2t_kernel<<<256, 256, 0, stream>>>(W_o2, Wo2t);
        gemm64_kernel<<<dim3(4, 16), 256, 0, stream>>>(A0, 1024, 256, W_init, 1024, 1024,
                                                       b_init, hbuf, 1024, 1);
        gemm64_kernel<<<dim3(1, 16), 256, 0, stream>>>(be, 512, 64, W_in + 512, 1024, 512,
                                                       nullptr, bpart, 1024, 0);
        gemm64_kernel<<<dim3(1, 16), 256, 0, stream>>>(gb, 1024, 2, W_o1, 1536, 1024,
                                                       nullptr, uvv, 1024, 0);
        gemm64_kernel<<<dim3(4, 16), 256, 0, stream>>>(ctx, LDA_CTX, 256, W_in, 1024, 512,
                                                       b_in, cin, 1024, 0);
        xbuild0s_kernel<<<256, 256, 0, stream>>>(cin, bpart, prev, xh, xl);
        // weight packs (fragment order + hi/lo split; wo1k scaled by ln_g)
        packb_kernel<<<12288, 256, 0, stream>>>(W_ih, 1024, 0, 3072, 1024, nullptr, wihP_h, wihP_l);
        packb_kernel<<<12288, 256, 0, stream>>>(W_hh, 1024, 0, 3072, 1024, nullptr, whhP_h, whhP_l);
        packb_kernel<<<4096, 256, 0, stream>>>(W_o1, 1536, 0, 1024, 1024, ln_g, wo1kP_h, wo1kP_l);
        packb_kernel<<<2048, 256, 0, stream>>>(W_o1, 1536, 1024, 1024, 512, nullptr, wo1cP_h, wo1cP_l);
        packb_kernel<<<2048, 256, 0, stream>>>(W_in, 1024, 0, 1024, 512, nullptr, wcinP_h, wcinP_l);
        // activation splits: h0, ctx slices 0 and 1
        wsplit_kernel<<<1024, 256, 0, stream>>>(hbuf, 1024, 0, 256, 1024, hh, hl);
        wsplit_kernel<<<512, 256, 0, stream>>>(ctx, LDA_CTX, 0, 256, 512, ctxh, ctxl);
        wsplit_kernel<<<512, 256, 0, stream>>>(ctx, LDA_CTX, 512, 256, 512,
                                               ctxh + 131072, ctxl + 131072);

        // ---- recurrence ----
        for (int t = 0; t < TT; ++t) {
            gates6_kernel<<<256, 512, 0, stream>>>(
                xh, xl, hh, hl, ctxh, ctxl,
                wihP_h, wihP_l, whhP_h, whhP_l, wcinP_h, wcinP_l, wo1cP_h, wo1cP_l,
                b_in, b_o1, g6, cin, octx, t);
            gru_ln6_kernel<<<256, 256, 0, stream>>>(g6, b_ih, b_hh, hbuf,
                                                    hh, hl, mbuf, isbuf);
            kb6_kernel<<<64, 256, 0, stream>>>(hh, hl, wo1kP_h, wo1kP_l,
                                               uvv, octx, mbuf, isbuf, obuf);
            kc2_kernel<<<64, 256, 0, stream>>>(obuf, Wo2t, b_o2, cin, bpart, ctx,
                                               xh, xl, ctxh, ctxl, prev, out, t);
        }
    } else {
        // ---- fallback: round-1 fp32 path ----
        float* A0    = ws;
        float* hbuf  = ws + 262144;
        float* hg    = ws + 786432;
        float* x     = ws + 1048576;
        float* cin   = ws + 1310720;
        float* octx  = ws + 1835008;
        float* g6    = ws + 2097152;
        float* obuf  = ws + 3670016;
        float* bpart = ws + 3932160;
        float* uvv   = ws + 3997696;
        float* gb    = ws + 3999744;
        float* Wo2t  = ws + 4001792;
        float* mbuf  = ws + 4067328;
        float* isbuf = ws + 4067584;
        int*   prev  = (int*)(ws + 4067840);

        pre0_kernel<<<256, 512, 0, stream>>>(ctx, bh, be, A0, prev);
        copy_gb_kernel<<<8, 256, 0, stream>>>(ln_g, ln_b, gb);
        wo2t_kernel<<<256, 256, 0, stream>>>(W_o2, Wo2t);
        gemm64_kernel<<<dim3(4, 16), 256, 0, stream>>>(A0, 1024, 256, W_init, 1024, 1024,
                                                       b_init, hbuf, 1024, 1);
        gemm64_kernel<<<dim3(1, 16), 256, 0, stream>>>(be, 512, 64, W_in + 512, 1024, 512,
                                                       nullptr, bpart, 1024, 0);
        gemm64_kernel<<<dim3(1, 16), 256, 0, stream>>>(gb, 1024, 2, W_o1, 1536, 1024,
                                                       nullptr, uvv, 1024, 0);
        gemm64_kernel<<<dim3(4, 16), 256, 0, stream>>>(ctx, LDA_CTX, 256, W_in, 1024, 512,
                                                       b_in, cin, 1024, 0);
        xbuild0_kernel<<<256, 256, 0, stream>>>(cin, bpart, prev, x);

        for (int t = 0; t < TT; ++t) {
            step_gemms_kernel<<<dim3(4, 16, 8), 256, 0, stream>>>(
                x, hbuf, ctx, W_ih, W_hh, W_in, W_o1, b_in, b_o1, g6, cin, octx, t);
            gru_ln_kernel<<<256, 256, 0, stream>>>(g6, b_ih, b_hh, hbuf, ln_g, hg,
                                                   mbuf, isbuf, t);
            kb_kernel<<<dim3(8, 16), 256, 0, stream>>>(hg, W_o1, uvv, octx, mbuf, isbuf, obuf);
            kc_kernel<<<256, 256, 0, stream>>>(obuf, Wo2t, b_o2, cin, bpart, x, prev, out, t);
        }
    }
}

// Round 7
// 7913.483 us; speedup vs baseline: 1.5147x; 1.5147x over previous
//
#include <hip/hip_runtime.h>
#include <hip/hip_bf16.h>

// ---------------------------------------------------------------------------
// AutoregressiveBeamDecoder: B=256, T=128, D=512, H=1024, NB=64, HH=8
// Round 7: LDS-staged split-bf16 MFMA, rebalanced.
//  - core: block 64x128, 4 waves, wave tile 32x64 (2 A-frags x 4 B-frags),
//    BK=32, double-buffered LDS (1 barrier/iter), reg prefetch at loop top
//  - gates: 256 blocks, bid = tile*8 + z  (XCD class = z -> B panel in L2)
//  - kb: K-split 4 -> 128 blocks; raw partials into g6 slots 0..3 (reuse);
//    LN epilogue + partial reduction fused into kc
// C = Ahi@Whi + Ahi@Wlo + Alo@Whi  (3x mfma_f32_16x16x32_bf16, fp32 accum)
// ---------------------------------------------------------------------------

#define TS 68          // fp32 LDS row stride (fallback path only)
#define LDPA 40        // bf16 LDS row stride (shorts): 80 B, 2-way max aliasing
constexpr int SZ = 262144;     // 256*1024
constexpr int TT = 128;        // T
constexpr int LDA_CTX = 65536; // T*D

typedef __attribute__((ext_vector_type(8))) short short8_t;
typedef __attribute__((ext_vector_type(4))) float f32x4;

// ---------------- bf16 split helpers (bit-level, RNE) ----------------------

__device__ __forceinline__ unsigned short f2bf_rne(float v) {
    unsigned u = __float_as_uint(v);
    unsigned r = u + 0x7fffu + ((u >> 16) & 1u);
    return (unsigned short)(r >> 16);
}
__device__ __forceinline__ float bfbits2f(unsigned short h) {
    return __uint_as_float(((unsigned)h) << 16);
}
__device__ __forceinline__ void split2(float v, unsigned short& h, unsigned short& l) {
    h = f2bf_rne(v);
    l = f2bf_rne(v - bfbits2f(h));
}

// ---------------- round-7 GEMM core ----------------------------------------
// block 64(M) x 128(N), 256 thr = 4 waves; wave (wr=wid>>1, wc=wid&1) owns
// 32x64 = 2 A-frags x 4 B-frags. BK=32, double-buffered.
// sm shorts: [2 bufs][ Ah 64*40 | Al 64*40 | Bh 128*40 | Bl 128*40 ] = 2*15360

__device__ __forceinline__ void mfma_core7(
    const unsigned short* __restrict__ Ah, const unsigned short* __restrict__ Al,
    int lda, int b0,
    const unsigned short* __restrict__ Bh, const unsigned short* __restrict__ Bl,
    int ldb, int n0, int k0base, int nIter,
    unsigned short* sm, f32x4 acc[2][4])
{
    const int tid = threadIdx.x, lane = tid & 63, wid = tid >> 6;
    const int wr = wid >> 1, wc = wid & 1;
    const int l15 = lane & 15, kg = (lane >> 4) * 8;
    const int arow = tid >> 2, acol = (tid & 3) * 8;   // A: 4 thr/row, 8 shorts
    const int brow = tid >> 1, bcol = (tid & 1) * 16;  // B: 2 thr/row, 16 shorts

    const int AOFF = 2560, BHOFF = 5120, BLOFF = 10240, BUF = 15360;

    const unsigned short* gAh = Ah + (size_t)(b0 + arow) * lda + k0base + acol;
    const unsigned short* gAl = Al + (size_t)(b0 + arow) * lda + k0base + acol;
    const unsigned short* gBh = Bh + (size_t)(n0 + brow) * ldb + k0base + bcol;
    const unsigned short* gBl = Bl + (size_t)(n0 + brow) * ldb + k0base + bcol;

    // prologue: stage k-tile 0 into buffer 0
    {
        short8_t a_h = *(const short8_t*)gAh;
        short8_t a_l = *(const short8_t*)gAl;
        short8_t bh0 = *(const short8_t*)gBh;
        short8_t bh1 = *(const short8_t*)(gBh + 8);
        short8_t bl0 = *(const short8_t*)gBl;
        short8_t bl1 = *(const short8_t*)(gBl + 8);
        *(short8_t*)&sm[arow * LDPA + acol]              = a_h;
        *(short8_t*)&sm[AOFF + arow * LDPA + acol]       = a_l;
        *(short8_t*)&sm[BHOFF + brow * LDPA + bcol]      = bh0;
        *(short8_t*)&sm[BHOFF + brow * LDPA + bcol + 8]  = bh1;
        *(short8_t*)&sm[BLOFF + brow * LDPA + bcol]      = bl0;
        *(short8_t*)&sm[BLOFF + brow * LDPA + bcol + 8]  = bl1;
    }
    __syncthreads();

    int cur = 0;
    const int aro = (wr * 32 + l15) * LDPA + kg;
    for (int i = 0; i < nIter; ++i) {
        short8_t a_h, a_l, bh0, bh1, bl0, bl1;
        if (i + 1 < nIter) {               // prefetch next tile (under compute)
            const int ko = (i + 1) * 32;
            a_h = *(const short8_t*)(gAh + ko);
            a_l = *(const short8_t*)(gAl + ko);
            bh0 = *(const short8_t*)(gBh + ko);
            bh1 = *(const short8_t*)(gBh + ko + 8);
            bl0 = *(const short8_t*)(gBl + ko);
            bl1 = *(const short8_t*)(gBl + ko + 8);
        }
        const unsigned short* S = sm + cur * BUF;
        short8_t afh[2], afl[2];
#pragma unroll
        for (int mi = 0; mi < 2; ++mi) {
            afh[mi] = *(const short8_t*)&S[aro + mi * 16 * LDPA];
            afl[mi] = *(const short8_t*)&S[AOFF + aro + mi * 16 * LDPA];
        }
#pragma unroll
        for (int ni = 0; ni < 4; ++ni) {
            const int bro = (wc * 64 + ni * 16 + l15) * LDPA + kg;
            short8_t b_h = *(const short8_t*)&S[BHOFF + bro];
            short8_t b_l = *(const short8_t*)&S[BLOFF + bro];
#pragma unroll
            for (int mi = 0; mi < 2; ++mi) {
                acc[mi][ni] = __builtin_amdgcn_mfma_f32_16x16x32_bf16(afh[mi], b_h, acc[mi][ni], 0, 0, 0);
                acc[mi][ni] = __builtin_amdgcn_mfma_f32_16x16x32_bf16(afh[mi], b_l, acc[mi][ni], 0, 0, 0);
                acc[mi][ni] = __builtin_amdgcn_mfma_f32_16x16x32_bf16(afl[mi], b_h, acc[mi][ni], 0, 0, 0);
            }
        }
        if (i + 1 < nIter) {
            unsigned short* N_ = sm + (cur ^ 1) * BUF;
            *(short8_t*)&N_[arow * LDPA + acol]             = a_h;
            *(short8_t*)&N_[AOFF + arow * LDPA + acol]      = a_l;
            *(short8_t*)&N_[BHOFF + brow * LDPA + bcol]     = bh0;
            *(short8_t*)&N_[BHOFF + brow * LDPA + bcol + 8] = bh1;
            *(short8_t*)&N_[BLOFF + brow * LDPA + bcol]     = bl0;
            *(short8_t*)&N_[BLOFF + brow * LDPA + bcol + 8] = bl1;
        }
        __syncthreads();
        cur ^= 1;
    }
}

// ---------------- fp32 tiled GEMM core (setup + fallback) ------------------

__device__ __forceinline__ void gemm_tile64(
    const float* __restrict__ A, int lda, int Mlim, int b0,
    const float* __restrict__ W, int ldw, int n0, int K,
    float* At, float* Wt, float acc[4][4])
{
    const int tid = threadIdx.x;
    const int tx = tid & 15, ty = tid >> 4;
    const int r = tid >> 2, c0 = (tid & 3) << 2;
    for (int k0 = 0; k0 < K; k0 += 16) {
        float4 av = make_float4(0.f, 0.f, 0.f, 0.f);
        if (b0 + r < Mlim)
            av = *(const float4*)(A + (size_t)(b0 + r) * lda + k0 + c0);
        float4 wv = *(const float4*)(W + (size_t)(n0 + r) * ldw + k0 + c0);
        __syncthreads();
        At[(c0+0)*TS + r] = av.x; At[(c0+1)*TS + r] = av.y;
        At[(c0+2)*TS + r] = av.z; At[(c0+3)*TS + r] = av.w;
        Wt[(c0+0)*TS + r] = wv.x; Wt[(c0+1)*TS + r] = wv.y;
        Wt[(c0+2)*TS + r] = wv.z; Wt[(c0+3)*TS + r] = wv.w;
        __syncthreads();
#pragma unroll
        for (int kk = 0; kk < 16; ++kk) {
            float4 a = *(const float4*)(At + kk*TS + ty*4);
            float4 w = *(const float4*)(Wt + kk*TS + tx*4);
            acc[0][0] += a.x*w.x; acc[0][1] += a.x*w.y; acc[0][2] += a.x*w.z; acc[0][3] += a.x*w.w;
            acc[1][0] += a.y*w.x; acc[1][1] += a.y*w.y; acc[1][2] += a.y*w.z; acc[1][3] += a.y*w.w;
            acc[2][0] += a.z*w.x; acc[2][1] += a.z*w.y; acc[2][2] += a.z*w.z; acc[2][3] += a.z*w.w;
            acc[3][0] += a.w*w.x; acc[3][1] += a.w*w.y; acc[3][2] += a.w*w.z; acc[3][3] += a.w*w.w;
        }
    }
}

// -------------------- setup kernels ----------------------------------------

__global__ void pre0_kernel(const float* __restrict__ ctx, const int* __restrict__ bh,
                            const float* __restrict__ be, float* __restrict__ A0,
                            int* __restrict__ prev)
{
    int b = blockIdx.x, tid = threadIdx.x; // blockDim 512
    float s = 0.f;
    for (int t = 0; t < TT; ++t) s += ctx[(size_t)b * LDA_CTX + t * 512 + tid];
    A0[b * 1024 + tid] = s * (1.f / 128.f);
    float s2 = 0.f;
    for (int i = 0; i < 8; ++i) s2 += be[bh[b * 8 + i] * 512 + tid];
    A0[b * 1024 + 512 + tid] = s2 * 0.125f;
    if (tid == 0) prev[b] = bh[b * 8 + 7];
}

__global__ void copy_gb_kernel(const float* g, const float* bb, float* gb)
{
    int idx = blockIdx.x * 256 + threadIdx.x; // 8 blocks
    if (idx < 1024) gb[idx] = g[idx];
    else            gb[idx] = bb[idx - 1024];
}

__global__ void wo2t_kernel(const float* __restrict__ W_o2, float* __restrict__ Wo2t)
{
    int idx = blockIdx.x * 256 + threadIdx.x; // 256 blocks -> 65536
    int k = idx >> 6, n = idx & 63;
    Wo2t[idx] = W_o2[n * 1024 + k];
}

// split matrix [N x K] (row stride src_ld, col offset col0, optional k-scale)
__global__ void wsplit_kernel(const float* __restrict__ src, int src_ld, int col0,
                              int N, int K, const float* __restrict__ scale,
                              unsigned short* __restrict__ hi,
                              unsigned short* __restrict__ lo)
{
    int idx = blockIdx.x * 256 + threadIdx.x;
    if (idx >= N * K) return;
    int n = idx / K, k = idx - n * K;
    float v = src[(size_t)n * src_ld + col0 + k];
    if (scale) v *= scale[k];
    unsigned short h, l;
    split2(v, h, l);
    hi[idx] = h; lo[idx] = l;
}

// generic small fp32 GEMM (M may be < 64); act: 0 none, 1 tanh
__global__ void gemm64_kernel(const float* __restrict__ A, int lda, int M,
                              const float* __restrict__ W, int ldw, int K,
                              const float* __restrict__ bias,
                              float* __restrict__ C, int ldc, int act)
{
    __shared__ __align__(16) float At[16 * TS];
    __shared__ __align__(16) float Wt[16 * TS];
    float acc[4][4] = {};
    int b0 = blockIdx.x * 64, n0 = blockIdx.y * 64;
    gemm_tile64(A, lda, M, b0, W, ldw, n0, K, At, Wt, acc);
    int tx = threadIdx.x & 15, ty = threadIdx.x >> 4;
#pragma unroll
    for (int i = 0; i < 4; ++i) {
        int b = b0 + ty * 4 + i;
        if (b >= M) continue;
#pragma unroll
        for (int j = 0; j < 4; ++j) {
            int n = n0 + tx * 4 + j;
            float v = acc[i][j] + (bias ? bias[n] : 0.f);
            if (act == 1) v = tanhf(v);
            C[(size_t)b * ldc + n] = v;
        }
    }
}

// x0 = relu(cin0 + bpart[prev]) -> split
__global__ void xbuild0s_kernel(const float* __restrict__ cin0, const float* __restrict__ bpart,
                                const int* __restrict__ prev,
                                unsigned short* __restrict__ xh, unsigned short* __restrict__ xl)
{
    int b = blockIdx.x, tid = threadIdx.x;
    int pb = prev[b];
#pragma unroll
    for (int jj = 0; jj < 4; ++jj) {
        int j = jj * 256 + tid;
        float v = fmaxf(cin0[(size_t)b * 1024 + j] + bpart[(size_t)pb * 1024 + j], 0.f);
        unsigned short h, l;
        split2(v, h, l);
        xh[(size_t)b * 1024 + j] = h;
        xl[(size_t)b * 1024 + j] = l;
    }
}

// fp32 xbuild (fallback)
__global__ void xbuild0_kernel(const float* __restrict__ cin0, const float* __restrict__ bpart,
                               const int* __restrict__ prev, float* __restrict__ x)
{
    int b = blockIdx.x, tid = threadIdx.x;
    int pb = prev[b];
#pragma unroll
    for (int jj = 0; jj < 4; ++jj) {
        int j = jj * 256 + tid;
        x[(size_t)b * 1024 + j] = fmaxf(cin0[(size_t)b * 1024 + j] + bpart[(size_t)pb * 1024 + j], 0.f);
    }
}

// -------------------- per-step MFMA kernels (round 7) ----------------------

// Fused 8-way GEMM; grid 256: bid = tile*8 + z, tile = tm*... (tm = tile&3,
// tn = tile>>2). XCD round-robin class = z -> that z's B panel stays in one L2.
__global__ __launch_bounds__(256) void gates7_kernel(
    const unsigned short* __restrict__ xh, const unsigned short* __restrict__ xl,
    const unsigned short* __restrict__ hh, const unsigned short* __restrict__ hl,
    const unsigned short* __restrict__ ctxh, const unsigned short* __restrict__ ctxl,
    const unsigned short* __restrict__ wih_hi, const unsigned short* __restrict__ wih_lo,
    const unsigned short* __restrict__ whh_hi, const unsigned short* __restrict__ whh_lo,
    const unsigned short* __restrict__ wcin_hi, const unsigned short* __restrict__ wcin_lo,
    const unsigned short* __restrict__ wo1c_hi, const unsigned short* __restrict__ wo1c_lo,
    const float* __restrict__ b_in, const float* __restrict__ b_o1,
    float* __restrict__ g6, float* __restrict__ cin, float* __restrict__ octx,
    int t)
{
    const int bid = blockIdx.x;
    const int z = bid & 7;
    const int tile = bid >> 3;
    const int tm = tile & 3, tn = tile >> 2;
    if (z == 6 && t + 1 >= TT) return;
    const int b0 = tm * 64, n0 = tn * 128;

    const unsigned short *Ah, *Al, *Bh, *Bl;
    int lda, ldb, nIter;
    const float* bias = nullptr;
    float* C;
    if (z < 6) {
        int g = z % 3, s = z / 3;
        Ah = s ? hh : xh; Al = s ? hl : xl; lda = 1024;
        Bh = (s ? whh_hi : wih_hi) + (size_t)g * 1048576;
        Bl = (s ? whh_lo : wih_lo) + (size_t)g * 1048576;
        ldb = 1024; nIter = 32;
        C = g6 + (size_t)z * SZ;
    } else if (z == 6) {
        int s = (t + 1) & 1;
        Ah = ctxh + (size_t)s * 131072; Al = ctxl + (size_t)s * 131072;
        lda = 512; ldb = 512; nIter = 16;
        Bh = wcin_hi; Bl = wcin_lo; bias = b_in; C = cin;
    } else {
        int s = t & 1;
        Ah = ctxh + (size_t)s * 131072; Al = ctxl + (size_t)s * 131072;
        lda = 512; ldb = 512; nIter = 16;
        Bh = wo1c_hi; Bl = wo1c_lo; bias = b_o1; C = octx;
    }

    __shared__ __align__(16) unsigned short sm[2 * 15360];
    f32x4 acc[2][4] = {};
    mfma_core7(Ah, Al, lda, b0, Bh, Bl, ldb, n0, 0, nIter, sm, acc);

    const int lane = threadIdx.x & 63, wid = threadIdx.x >> 6;
    const int wr = wid >> 1, wc = wid & 1;
    const int l15 = lane & 15, g4 = (lane >> 4) * 4;
#pragma unroll
    for (int mi = 0; mi < 2; ++mi) {
#pragma unroll
        for (int ni = 0; ni < 4; ++ni) {
            int col = n0 + wc * 64 + ni * 16 + l15;
            float bv = bias ? bias[col] : 0.f;
#pragma unroll
            for (int r = 0; r < 4; ++r) {
                int row = b0 + wr * 32 + mi * 16 + g4 + r;
                C[(size_t)row * 1024 + col] = acc[mi][ni][r] + bv;
            }
        }
    }
}

// o-GEMM raw partials, K-split 4 into g6 slots 0..3; grid 128:
// bid = tm*32 + tn*4 + p
__global__ __launch_bounds__(256) void kb7_kernel(
    const unsigned short* __restrict__ hh, const unsigned short* __restrict__ hl,
    const unsigned short* __restrict__ wo1k_hi, const unsigned short* __restrict__ wo1k_lo,
    float* __restrict__ g6)
{
    const int bid = blockIdx.x;
    const int tm = bid >> 5, tn = (bid >> 2) & 7, p = bid & 3;
    const int b0 = tm * 64, n0 = tn * 128, k0 = p * 256;

    __shared__ __align__(16) unsigned short sm[2 * 15360];
    f32x4 acc[2][4] = {};
    mfma_core7(hh, hl, 1024, b0, wo1k_hi, wo1k_lo, 1024, n0, k0, 8, sm, acc);

    float* C = g6 + (size_t)p * SZ;
    const int lane = threadIdx.x & 63, wid = threadIdx.x >> 6;
    const int wr = wid >> 1, wc = wid & 1;
    const int l15 = lane & 15, g4 = (lane >> 4) * 4;
#pragma unroll
    for (int mi = 0; mi < 2; ++mi) {
#pragma unroll
        for (int ni = 0; ni < 4; ++ni) {
            int col = n0 + wc * 64 + ni * 16 + l15;
#pragma unroll
            for (int r = 0; r < 4; ++r) {
                int row = b0 + wr * 32 + mi * 16 + g4 + r;
                C[(size_t)row * 1024 + col] = acc[mi][ni][r];
            }
        }
    }
}

// GRU combine + LN stats; writes h fp32 in-place + split h
__global__ void gru_ln6_kernel(const float* __restrict__ g6,
                               const float* __restrict__ b_ih, const float* __restrict__ b_hh,
                               float* __restrict__ h,
                               unsigned short* __restrict__ hh, unsigned short* __restrict__ hl,
                               float* __restrict__ mbuf, float* __restrict__ isbuf)
{
    __shared__ float ls[4], lq[4];
    int b = blockIdx.x, tid = threadIdx.x;
    float s = 0.f, q = 0.f;
#pragma unroll
    for (int jj = 0; jj < 4; ++jj) {
        int j = jj * 256 + tid;
        size_t base = (size_t)b * 1024 + j;
        float xr = g6[0 * (size_t)SZ + base] + b_ih[j];
        float xz = g6[1 * (size_t)SZ + base] + b_ih[1024 + j];
        float xn = g6[2 * (size_t)SZ + base] + b_ih[2048 + j];
        float hr = g6[3 * (size_t)SZ + base] + b_hh[j];
        float hz = g6[4 * (size_t)SZ + base] + b_hh[1024 + j];
        float hn = g6[5 * (size_t)SZ + base] + b_hh[2048 + j];
        float r = 1.f / (1.f + expf(-(xr + hr)));
        float z = 1.f / (1.f + expf(-(xz + hz)));
        float nn = tanhf(xn + r * hn);
        float ho = h[base];
        float hv = (1.f - z) * nn + z * ho;
        h[base] = hv;
        unsigned short a, c;
        split2(hv, a, c); hh[base] = a; hl[base] = c;
        s += hv; q += hv * hv;
    }
    for (int off = 32; off; off >>= 1) {
        s += __shfl_down(s, off);
        q += __shfl_down(q, off);
    }
    int lane = tid & 63, w = tid >> 6;
    if (lane == 0) { ls[w] = s; lq[w] = q; }
    __syncthreads();
    if (tid == 0) {
        float S = ls[0] + ls[1] + ls[2] + ls[3];
        float Q = lq[0] + lq[1] + lq[2] + lq[3];
        float m = S * (1.f / 1024.f);
        mbuf[b] = m;
        isbuf[b] = rsqrtf(Q * (1.f / 1024.f) - m * m + 1e-5f);
    }
}

// partial-sum + LN epilogue + logits + argmax + x-build + ctx-split
// 64 blocks x 256 thr, 4 rows each
__global__ void kc7_kernel(const float* __restrict__ g6,
                           const float* __restrict__ Wo2t, const float* __restrict__ b_o2,
                           const float* __restrict__ uv, const float* __restrict__ octx,
                           const float* __restrict__ mbuf, const float* __restrict__ isbuf,
                           const float* __restrict__ cin, const float* __restrict__ bpart,
                           const float* __restrict__ ctx,
                           unsigned short* __restrict__ xh, unsigned short* __restrict__ xl,
                           unsigned short* __restrict__ ctxh, unsigned short* __restrict__ ctxl,
                           int* __restrict__ prev, float* __restrict__ out, int t)
{
    __shared__ __align__(16) float os[4][1024];
    __shared__ float red[4][4][64];
    __shared__ int sidx[4];
    const int b0 = blockIdx.x * 4, tid = threadIdx.x;

    // o = relu((P - m*u)*is + v + octx), P = sum of 4 K-split partials
#pragma unroll
    for (int i = 0; i < 4; ++i) {
        int f = tid + i * 256;             // float4 index, 0..1023
        int r = f >> 8, c4 = (f & 255) << 2;
        size_t base = (size_t)(b0 + r) * 1024 + c4;
        float4 p0 = *(const float4*)(g6 + base);
        float4 p1 = *(const float4*)(g6 + (size_t)SZ + base);
        float4 p2 = *(const float4*)(g6 + 2 * (size_t)SZ + base);
        float4 p3 = *(const float4*)(g6 + 3 * (size_t)SZ + base);
        float4 oc = *(const float4*)(octx + base);
        float4 u4 = *(const float4*)(uv + c4);
        float4 v4 = *(const float4*)(uv + 1024 + c4);
        float m = mbuf[b0 + r], is = isbuf[b0 + r];
        float4 o4;
        o4.x = fmaxf((p0.x + p1.x + p2.x + p3.x - m * u4.x) * is + v4.x + oc.x, 0.f);
        o4.y = fmaxf((p0.y + p1.y + p2.y + p3.y - m * u4.y) * is + v4.y + oc.y, 0.f);
        o4.z = fmaxf((p0.z + p1.z + p2.z + p3.z - m * u4.z) * is + v4.z + oc.z, 0.f);
        o4.w = fmaxf((p0.w + p1.w + p2.w + p3.w - m * u4.w) * is + v4.w + oc.w, 0.f);
        *(float4*)&os[r][c4] = o4;
    }
    __syncthreads();

    {
        int n = tid & 63, seg = tid >> 6;
        float p0 = 0.f, p1 = 0.f, p2 = 0.f, p3 = 0.f;
        int k0 = seg * 256;
        for (int k = k0; k < k0 + 256; ++k) {
            float w = Wo2t[(size_t)k * 64 + n];
            p0 += os[0][k] * w; p1 += os[1][k] * w;
            p2 += os[2][k] * w; p3 += os[3][k] * w;
        }
        red[0][seg][n] = p0; red[1][seg][n] = p1;
        red[2][seg][n] = p2; red[3][seg][n] = p3;
    }
    __syncthreads();

    {
        int r = tid >> 6, n = tid & 63;
        float lg = red[r][0][n] + red[r][1][n] + red[r][2][n] + red[r][3][n] + b_o2[n];
        out[(size_t)(b0 + r) * (TT * 64) + t * 64 + n] = lg;
        float v = lg; int idx = n;
        for (int off = 32; off; off >>= 1) {
            float ov = __shfl_xor(v, off);
            int oi = __shfl_xor(idx, off);
            if (ov > v || (ov == v && oi < idx)) { v = ov; idx = oi; }
        }
        if (n == 0) { prev[b0 + r] = idx; sidx[r] = idx; }
    }
    __syncthreads();

    if (t + 1 < TT) {
#pragma unroll
        for (int i = 0; i < 16; ++i) {
            int idx = tid + i * 256;       // 0..4095
            int r = idx >> 10, j = idx & 1023;
            float v = fmaxf(cin[(size_t)(b0 + r) * 1024 + j] +
                            bpart[(size_t)sidx[r] * 1024 + j], 0.f);
            unsigned short h, l;
            split2(v, h, l);
            xh[(size_t)(b0 + r) * 1024 + j] = h;
            xl[(size_t)(b0 + r) * 1024 + j] = l;
        }
    }
    if (t + 2 < TT) {
        int slot = t & 1;
#pragma unroll
        for (int i = 0; i < 8; ++i) {
            int idx = tid + i * 256;       // 0..2047
            int r = idx >> 9, j = idx & 511;
            float v = ctx[(size_t)(b0 + r) * LDA_CTX + (t + 2) * 512 + j];
            unsigned short h, l;
            split2(v, h, l);
            ctxh[(size_t)slot * 131072 + (size_t)(b0 + r) * 512 + j] = h;
            ctxl[(size_t)slot * 131072 + (size_t)(b0 + r) * 512 + j] = l;
        }
    }
}

// -------------------- fallback fp32 step kernels (round 1) -----------------

__global__ void step_gemms_kernel(
    const float* __restrict__ x, const float* __restrict__ hBase,
    const float* __restrict__ ctx,
    const float* __restrict__ Wih, const float* __restrict__ Whh,
    const float* __restrict__ Win, const float* __restrict__ Wo1,
    const float* __restrict__ b_in, const float* __restrict__ b_o1,
    float* __restrict__ g6, float* __restrict__ cinBase, float* __restrict__ octx,
    int t)
{
    __shared__ __align__(16) float At[16 * TS];
    __shared__ __align__(16) float Wt[16 * TS];
    float acc[4][4] = {};
    const int z = blockIdx.z, b0 = blockIdx.x * 64, n0 = blockIdx.y * 64;
    const float *A, *W, *bias = nullptr;
    float* C;
    int lda, ldw, K;
    if (z < 6) {
        int g = z % 3, s = z / 3;
        A = s ? (hBase + (size_t)(t & 1) * SZ) : x;
        lda = 1024;
        W = (s ? Whh : Wih) + (size_t)(g * 1024) * 1024;
        ldw = 1024; K = 1024;
        C = g6 + (size_t)z * SZ;
    } else if (z == 6) {
        if (t + 1 >= TT) return;
        A = ctx + (size_t)(t + 1) * 512; lda = LDA_CTX;
        W = Win; ldw = 1024; K = 512; bias = b_in;
        C = cinBase + (size_t)((t + 1) & 1) * SZ;
    } else {
        A = ctx + (size_t)t * 512; lda = LDA_CTX;
        W = Wo1 + 1024; ldw = 1536; K = 512; bias = b_o1;
        C = octx;
    }
    gemm_tile64(A, lda, 256, b0, W, ldw, n0, K, At, Wt, acc);
    int tx = threadIdx.x & 15, ty = threadIdx.x >> 4;
#pragma unroll
    for (int i = 0; i < 4; ++i) {
        int b = b0 + ty * 4 + i;
#pragma unroll
        for (int j = 0; j < 4; ++j) {
            int n = n0 + tx * 4 + j;
            float v = acc[i][j];
            if (bias) v += bias[n];
            C[(size_t)b * 1024 + n] = v;
        }
    }
}

__global__ void kb_kernel(const float* __restrict__ hg, const float* __restrict__ Wo1,
                          const float* __restrict__ uv, const float* __restrict__ octx,
                          const float* __restrict__ mbuf, const float* __restrict__ isbuf,
                          float* __restrict__ o)
{
    __shared__ __align__(16) float At[16 * TS];
    __shared__ __align__(16) float Wt[16 * TS];
    float acc[2][4] = {};
    const int b0 = blockIdx.x * 32, n0 = blockIdx.y * 64;
    const int tid = threadIdx.x, tx = tid & 15, ty = tid >> 4;
    const int r = tid >> 2, c0 = (tid & 3) << 2;
    for (int k0 = 0; k0 < 1024; k0 += 16) {
        float4 av = make_float4(0.f, 0.f, 0.f, 0.f);
        if (r < 32) av = *(const float4*)(hg + (size_t)(b0 + r) * 1024 + k0 + c0);
        float4 wv = *(const float4*)(Wo1 + (size_t)(n0 + r) * 1536 + k0 + c0);
        __syncthreads();
        At[(c0+0)*TS + r] = av.x; At[(c0+1)*TS + r] = av.y;
        At[(c0+2)*TS + r] = av.z; At[(c0+3)*TS + r] = av.w;
        Wt[(c0+0)*TS + r] = wv.x; Wt[(c0+1)*TS + r] = wv.y;
        Wt[(c0+2)*TS + r] = wv.z; Wt[(c0+3)*TS + r] = wv.w;
        __syncthreads();
#pragma unroll
        for (int kk = 0; kk < 16; ++kk) {
            float2 a = *(const float2*)(At + kk*TS + ty*2);
            float4 w = *(const float4*)(Wt + kk*TS + tx*4);
            acc[0][0] += a.x*w.x; acc[0][1] += a.x*w.y; acc[0][2] += a.x*w.z; acc[0][3] += a.x*w.w;
            acc[1][0] += a.y*w.x; acc[1][1] += a.y*w.y; acc[1][2] += a.y*w.z; acc[1][3] += a.y*w.w;
        }
    }
#pragma unroll
    for (int i = 0; i < 2; ++i) {
        int b = b0 + ty * 2 + i;
        float m = mbuf[b], is = isbuf[b];
#pragma unroll
        for (int j = 0; j < 4; ++j) {
            int n = n0 + tx * 4 + j;
            float v = (acc[i][j] - m * uv[n]) * is + uv[1024 + n] + octx[(size_t)b * 1024 + n];
            o[(size_t)b * 1024 + n] = fmaxf(v, 0.f);
        }
    }
}

__global__ void gru_ln_kernel(const float* __restrict__ g6,
                              const float* __restrict__ b_ih, const float* __restrict__ b_hh,
                              float* __restrict__ hBase, const float* __restrict__ ln_g,
                              float* __restrict__ hg, float* __restrict__ mbuf,
                              float* __restrict__ isbuf, int t)
{
    __shared__ float rs[256], rq[256];
    int b = blockIdx.x, tid = threadIdx.x;
    const float* hc = hBase + (size_t)(t & 1) * SZ + (size_t)b * 1024;
    float* hnx = hBase + (size_t)((t + 1) & 1) * SZ + (size_t)b * 1024;
    float s = 0.f, q = 0.f;
#pragma unroll
    for (int jj = 0; jj < 4; ++jj) {
        int j = jj * 256 + tid;
        size_t base = (size_t)b * 1024 + j;
        float xr = g6[0 * (size_t)SZ + base] + b_ih[j];
        float xz = g6[1 * (size_t)SZ + base] + b_ih[1024 + j];
        float xn = g6[2 * (size_t)SZ + base] + b_ih[2048 + j];
        float hr = g6[3 * (size_t)SZ + base] + b_hh[j];
        float hz = g6[4 * (size_t)SZ + base] + b_hh[1024 + j];
        float hn = g6[5 * (size_t)SZ + base] + b_hh[2048 + j];
        float r = 1.f / (1.f + expf(-(xr + hr)));
        float z = 1.f / (1.f + expf(-(xz + hz)));
        float nn = tanhf(xn + r * hn);
        float ho = hc[j];
        float hv = (1.f - z) * nn + z * ho;
        hnx[j] = hv;
        hg[base] = hv * ln_g[j];
        s += hv; q += hv * hv;
    }
    rs[tid] = s; rq[tid] = q;
    __syncthreads();
    for (int st = 128; st; st >>= 1) {
        if (tid < st) { rs[tid] += rs[tid + st]; rq[tid] += rq[tid + st]; }
        __syncthreads();
    }
    if (tid == 0) {
        float m = rs[0] * (1.f / 1024.f);
        float var = rq[0] * (1.f / 1024.f) - m * m;
        mbuf[b] = m;
        isbuf[b] = rsqrtf(var + 1e-5f);
    }
}

__global__ void kc_kernel(const float* __restrict__ o, const float* __restrict__ Wo2t,
                          const float* __restrict__ b_o2, const float* __restrict__ cinBase,
                          const float* __restrict__ bpart, float* __restrict__ x,
                          int* __restrict__ prev, float* __restrict__ out, int t)
{
    __shared__ __align__(16) float os[1024];
    __shared__ float red[4][64];
    __shared__ int sidx;
    int b = blockIdx.x, tid = threadIdx.x;
    const float* orow = o + (size_t)b * 1024;
    *(float4*)&os[tid * 4] = *(const float4*)&orow[tid * 4];
    __syncthreads();
    int n = tid & 63, seg = tid >> 6;
    float p = 0.f;
    int k0 = seg * 256;
#pragma unroll 8
    for (int k = 0; k < 256; ++k) p += os[k0 + k] * Wo2t[(size_t)(k0 + k) * 64 + n];
    red[seg][n] = p;
    __syncthreads();
    if (tid < 64) {
        float lg = red[0][tid] + red[1][tid] + red[2][tid] + red[3][tid] + b_o2[tid];
        out[((size_t)b * TT + t) * 64 + tid] = lg;
        float v = lg; int idx = tid;
        for (int off = 32; off; off >>= 1) {
            float ov = __shfl_xor(v, off);
            int oi = __shfl_xor(idx, off);
            if (ov > v || (ov == v && oi < idx)) { v = ov; idx = oi; }
        }
        if (tid == 0) { prev[b] = idx; sidx = idx; }
    }
    __syncthreads();
    if (t + 1 < TT) {
        int pb = sidx;
        const float* cn = cinBase + (size_t)((t + 1) & 1) * SZ + (size_t)b * 1024;
        const float* bp = bpart + (size_t)pb * 1024;
#pragma unroll
        for (int jj = 0; jj < 4; ++jj) {
            int j = jj * 256 + tid;
            x[(size_t)b * 1024 + j] = fmaxf(cn[j] + bp[j], 0.f);
        }
    }
}

// ---------------------------------------------------------------------------

extern "C" void kernel_launch(void* const* d_in, const int* in_sizes, int n_in,
                              void* d_out, int out_size, void* d_ws, size_t ws_size,
                              hipStream_t stream)
{
    const float* ctx    = (const float*)d_in[0];
    const int*   bh     = (const int*)d_in[1];
    const float* be     = (const float*)d_in[2];
    const float* W_in   = (const float*)d_in[3];
    const float* b_in   = (const float*)d_in[4];
    const float* W_init = (const float*)d_in[5];
    const float* b_init = (const float*)d_in[6];
    const float* W_ih   = (const float*)d_in[7];
    const float* b_ih   = (const float*)d_in[8];
    const float* W_hh   = (const float*)d_in[9];
    const float* b_hh   = (const float*)d_in[10];
    const float* ln_g   = (const float*)d_in[11];
    const float* ln_b   = (const float*)d_in[12];
    const float* W_o1   = (const float*)d_in[13];
    const float* b_o1   = (const float*)d_in[14];
    const float* W_o2   = (const float*)d_in[15];
    const float* b_o2   = (const float*)d_in[16];
    float* out = (float*)d_out;
    float* ws  = (float*)d_ws;

    const bool mfma_path = (ws_size >= 49830000ull);

    if (mfma_path) {
        // ---- round-7 layout (floats) ----
        float* hbuf  = ws;                  // 256x1024 fp32, in-place h
        float* cin   = ws + 262144;
        float* octx  = ws + 524288;
        float* g6    = ws + 786432;         // 6 slots; slots 0..3 reused as kb partials
        float* A0    = g6;                  // setup-only alias (consumed before gates)
        float* bpart = ws + 2359296;        // 64x1024
        float* uvv   = ws + 2424832;        // 2x1024
        float* gb    = ws + 2426880;        // 2x1024
        float* Wo2t  = ws + 2428928;        // 1024x64
        float* mbuf  = ws + 2494464;
        float* isbuf = ws + 2494720;
        int*   prev  = (int*)(ws + 2494976);
        unsigned short* bf = (unsigned short*)(ws + 2495232);
        unsigned short* wih_hi  = bf;                   // [3072x1024]
        unsigned short* wih_lo  = bf + 3145728;
        unsigned short* whh_hi  = bf + 6291456;
        unsigned short* whh_lo  = bf + 9437184;
        unsigned short* wo1k_hi = bf + 12582912;        // [1024x1024], ln_g-folded
        unsigned short* wo1k_lo = bf + 13631488;
        unsigned short* wo1c_hi = bf + 14680064;        // [1024x512]
        unsigned short* wo1c_lo = bf + 15204352;
        unsigned short* wcin_hi = bf + 15728640;        // [1024x512]
        unsigned short* wcin_lo = bf + 16252928;
        unsigned short* xh   = bf + 16777216;
        unsigned short* xl   = bf + 17039360;
        unsigned short* hh   = bf + 17301504;
        unsigned short* hl   = bf + 17563648;
        unsigned short* ctxh = bf + 17825792;           // [2][256][512]
        unsigned short* ctxl = bf + 18087936;

        // ---- setup ----
        pre0_kernel<<<256, 512, 0, stream>>>(ctx, bh, be, A0, prev);
        copy_gb_kernel<<<8, 256, 0, stream>>>(ln_g, ln_b, gb);
        wo2t_kernel<<<256, 256, 0, stream>>>(W_o2, Wo2t);
        gemm64_kernel<<<dim3(4, 16), 256, 0, stream>>>(A0, 1024, 256, W_init, 1024, 1024,
                                                       b_init, hbuf, 1024, 1);
        gemm64_kernel<<<dim3(1, 16), 256, 0, stream>>>(be, 512, 64, W_in + 512, 1024, 512,
                                                       nullptr, bpart, 1024, 0);
        gemm64_kernel<<<dim3(1, 16), 256, 0, stream>>>(gb, 1024, 2, W_o1, 1536, 1024,
                                                       nullptr, uvv, 1024, 0);
        gemm64_kernel<<<dim3(4, 16), 256, 0, stream>>>(ctx, LDA_CTX, 256, W_in, 1024, 512,
                                                       b_in, cin, 1024, 0);
        xbuild0s_kernel<<<256, 256, 0, stream>>>(cin, bpart, prev, xh, xl);
        // weight splits (row-major hi/lo; wo1k scaled by ln_g)
        wsplit_kernel<<<12288, 256, 0, stream>>>(W_ih, 1024, 0, 3072, 1024, nullptr, wih_hi, wih_lo);
        wsplit_kernel<<<12288, 256, 0, stream>>>(W_hh, 1024, 0, 3072, 1024, nullptr, whh_hi, whh_lo);
        wsplit_kernel<<<4096, 256, 0, stream>>>(W_o1, 1536, 0, 1024, 1024, ln_g, wo1k_hi, wo1k_lo);
        wsplit_kernel<<<2048, 256, 0, stream>>>(W_o1, 1536, 1024, 1024, 512, nullptr, wo1c_hi, wo1c_lo);
        wsplit_kernel<<<2048, 256, 0, stream>>>(W_in, 1024, 0, 1024, 512, nullptr, wcin_hi, wcin_lo);
        // activation splits: h0, ctx slices 0 and 1
        wsplit_kernel<<<1024, 256, 0, stream>>>(hbuf, 1024, 0, 256, 1024, nullptr, hh, hl);
        wsplit_kernel<<<512, 256, 0, stream>>>(ctx, LDA_CTX, 0, 256, 512, nullptr, ctxh, ctxl);
        wsplit_kernel<<<512, 256, 0, stream>>>(ctx, LDA_CTX, 512, 256, 512, nullptr,
                                               ctxh + 131072, ctxl + 131072);

        // ---- recurrence ----
        for (int t = 0; t < TT; ++t) {
            gates7_kernel<<<256, 256, 0, stream>>>(
                xh, xl, hh, hl, ctxh, ctxl,
                wih_hi, wih_lo, whh_hi, whh_lo, wcin_hi, wcin_lo, wo1c_hi, wo1c_lo,
                b_in, b_o1, g6, cin, octx, t);
            gru_ln6_kernel<<<256, 256, 0, stream>>>(g6, b_ih, b_hh, hbuf,
                                                    hh, hl, mbuf, isbuf);
            kb7_kernel<<<128, 256, 0, stream>>>(hh, hl, wo1k_hi, wo1k_lo, g6);
            kc7_kernel<<<64, 256, 0, stream>>>(g6, Wo2t, b_o2, uvv, octx, mbuf, isbuf,
                                               cin, bpart, ctx, xh, xl, ctxh, ctxl,
                                               prev, out, t);
        }
    } else {
        // ---- fallback: round-1 fp32 path ----
        float* A0    = ws;
        float* hbuf  = ws + 262144;
        float* hg    = ws + 786432;
        float* x     = ws + 1048576;
        float* cin   = ws + 1310720;
        float* octx  = ws + 1835008;
        float* g6    = ws + 2097152;
        float* obuf  = ws + 3670016;
        float* bpart = ws + 3932160;
        float* uvv   = ws + 3997696;
        float* gb    = ws + 3999744;
        float* Wo2t  = ws + 4001792;
        float* mbuf  = ws + 4067328;
        float* isbuf = ws + 4067584;
        int*   prev  = (int*)(ws + 4067840);

        pre0_kernel<<<256, 512, 0, stream>>>(ctx, bh, be, A0, prev);
        copy_gb_kernel<<<8, 256, 0, stream>>>(ln_g, ln_b, gb);
        wo2t_kernel<<<256, 256, 0, stream>>>(W_o2, Wo2t);
        gemm64_kernel<<<dim3(4, 16), 256, 0, stream>>>(A0, 1024, 256, W_init, 1024, 1024,
                                                       b_init, hbuf, 1024, 1);
        gemm64_kernel<<<dim3(1, 16), 256, 0, stream>>>(be, 512, 64, W_in + 512, 1024, 512,
                                                       nullptr, bpart, 1024, 0);
        gemm64_kernel<<<dim3(1, 16), 256, 0, stream>>>(gb, 1024, 2, W_o1, 1536, 1024,
                                                       nullptr, uvv, 1024, 0);
        gemm64_kernel<<<dim3(4, 16), 256, 0, stream>>>(ctx, LDA_CTX, 256, W_in, 1024, 512,
                                                       b_in, cin, 1024, 0);
        xbuild0_kernel<<<256, 256, 0, stream>>>(cin, bpart, prev, x);

        for (int t = 0; t < TT; ++t) {
            step_gemms_kernel<<<dim3(4, 16, 8), 256, 0, stream>>>(
                x, hbuf, ctx, W_ih, W_hh, W_in, W_o1, b_in, b_o1, g6, cin, octx, t);
            gru_ln_kernel<<<256, 256, 0, stream>>>(g6, b_ih, b_hh, hbuf, ln_g, hg,
                                                   mbuf, isbuf, t);
            kb_kernel<<<dim3(8, 16), 256, 0, stream>>>(hg, W_o1, uvv, octx, mbuf, isbuf, obuf);
            kc_kernel<<<256, 256, 0, stream>>>(obuf, Wo2t, b_o2, cin, bpart, x, prev, out, t);
        }
    }
}